// Round 15
// baseline (1180.707 us; speedup 1.0000x reference)
//
#include <hip/hip_runtime.h>
#include <math.h>

#define S_LEN 2048
#define DHEAD 64
#define NBINS 512
#define BPL (NBINS / 64)
#define CANDMAX 48
#define NBH 64
#define NROWS (NBH * S_LEN)                   // 32768
#define VT_BYTES  (64ull * DHEAD * S_LEN * 2)   // 16 MB fp16 V^T
#define KHL_BYTES (64ull * S_LEN * 256)         // 33.5 MB hi/lo fp16 K
#define WS_NEED   (VT_BYTES + KHL_BYTES)

typedef _Float16 f16x8 __attribute__((ext_vector_type(8)));
typedef float    f32x4 __attribute__((ext_vector_type(4)));

// ---------------------------------------------------------------------------
// Kernel P1: K fp32 -> interleaved hi/lo fp16  ([key][hi 128B][lo 128B])
// ---------------------------------------------------------------------------
__global__ __launch_bounds__(256)
void prep_khl(const float* __restrict__ K, char* __restrict__ Khl) {
  int c = (int)(blockIdx.x * 256 + threadIdx.x);   // 1,048,576 chunks of 8 floats
  int keyg = c >> 3;            // global key row (bh*2048 + key)
  int ch   = c & 7;             // 8-float chunk within the 64-d row
  const float* src = K + (size_t)keyg * DHEAD + ch * 8;
  float4 a = *(const float4*)(src);
  float4 b = *(const float4*)(src + 4);
  float x[8] = {a.x, a.y, a.z, a.w, b.x, b.y, b.z, b.w};
  f16x8 hi, lo;
  #pragma unroll
  for (int j = 0; j < 8; ++j) {
    _Float16 h = (_Float16)x[j];
    hi[j] = h;
    lo[j] = (_Float16)(x[j] - (float)h);
  }
  char* dst = Khl + (size_t)keyg * 256 + ch * 16;
  *(f16x8*)(dst)       = hi;
  *(f16x8*)(dst + 128) = lo;
}

// ---------------------------------------------------------------------------
// Kernel P2: V fp32 -> V^T fp16 (VT[bh][dim][key]); one-time.
// ---------------------------------------------------------------------------
__global__ __launch_bounds__(256)
void prep_vt(const float* __restrict__ V, _Float16* __restrict__ VT) {
  const int bh  = (int)blockIdx.x >> 3;
  const int dg8 = (int)blockIdx.x & 7;
  const int t   = (int)threadIdx.x;
  const int dim = dg8 * 8 + (t >> 5);
  const int kc  = t & 31;
  const float* Vb = V + (size_t)bh * (S_LEN * DHEAD);
  _Float16* VTb = VT + ((size_t)bh * DHEAD + dim) * S_LEN;
  for (int i = 0; i < 8; ++i) {
    int key0 = (kc + i * 32) * 8;
    f16x8 h;
    #pragma unroll
    for (int j = 0; j < 8; ++j)
      h[j] = (_Float16)Vb[(size_t)(key0 + j) * DHEAD + dim];
    *(f16x8*)(VTb + key0) = h;
  }
}

// ---------------------------------------------------------------------------
// FUSED kernel: QK^T from precomputed hi/lo fp16 K (pure copies into swizzled
// LDS) + top-k selection + masked softmax + PV via MFMA against VT.
// 16 rows/block, 512 thr, grid 2048. launch_bounds(512,2): 256-VGPR budget,
// NO SPILL (sreg[16] = 64 regs fits). 1 block/CU.
// ---------------------------------------------------------------------------
__global__ __launch_bounds__(512, 2)
void fused_kernel(const float* __restrict__ Q, const char* __restrict__ Khl,
                  const _Float16* __restrict__ VT, const int* __restrict__ nkp,
                  float* __restrict__ Out) {
  __shared__ __align__(16) char smem[74752];
  unsigned* hist = (unsigned*)smem;
  float*    cand = (float*)(smem + 65536);
  unsigned* ccnt = (unsigned*)(smem + 68608);
  float*    pmax = (float*)(smem + 68672);
  float*    pmin = (float*)(smem + 69184);
  float*    rmax = (float*)(smem + 69696);
  float*    rmin = (float*)(smem + 69760);
  int*      bselA = (int*)(smem + 69824);
  int*      mthA  = (int*)(smem + 69888);
  int*      nbinA = (int*)(smem + 69952);
  float*    thrA  = (float*)(smem + 70016);
  float*    psp   = (float*)(smem + 70080);
  float*    psumA = (float*)(smem + 70592);
  float4*   redS  = (float4*)(smem + 70656);

  const int tid  = (int)threadIdx.x;
  const int lane = tid & 63;
  const int wid  = tid >> 6;                   // 0..7
  const int nxl  = (int)gridDim.x >> 3;        // 256
  const int xcd  = (int)blockIdx.x & 7;
  const int lbk  = (int)blockIdx.x >> 3;
  const int rowb = xcd * (nxl * 16) + lbk * 16;
  const int bh   = rowb >> 11;

  int nk = nkp[0];
  if (nk > S_LEN) nk = S_LEN;

  const int g = lane >> 4;
  const int m = lane & 15;

  // ---- A fragments (Q rows rowb+m), hi/lo split ----
  f16x8 a_hi0, a_lo0, a_hi1, a_lo1;
  {
    const float* Qrow = Q + (size_t)(rowb + m) * DHEAD;
    float4 qa = *(const float4*)(Qrow + g * 8);
    float4 qb = *(const float4*)(Qrow + g * 8 + 4);
    float4 qc = *(const float4*)(Qrow + 32 + g * 8);
    float4 qd = *(const float4*)(Qrow + 32 + g * 8 + 4);
    float x[16] = {qa.x,qa.y,qa.z,qa.w, qb.x,qb.y,qb.z,qb.w,
                   qc.x,qc.y,qc.z,qc.w, qd.x,qd.y,qd.z,qd.w};
    #pragma unroll
    for (int j = 0; j < 8; ++j) {
      _Float16 h0 = (_Float16)x[j];
      a_hi0[j] = h0;  a_lo0[j] = (_Float16)(x[j] - (float)h0);
      _Float16 h1 = (_Float16)x[8 + j];
      a_hi1[j] = h1;  a_lo1[j] = (_Float16)(x[8 + j] - (float)h1);
    }
  }

  const char* Kbh = Khl + (size_t)bh * (S_LEN * 256);

  // ---- QK: 16 tiles of 128 keys; S accumulates in registers ----
  // lane's S values: row = g*4+rg, key(t) = t*128 + wid*16 + m
  f32x4 sreg[16];
  #pragma unroll
  for (int t = 0; t < 16; ++t) {
    {
      // pure copy: 2048 f16x8 units (128 keys x 8 chunks x hi/lo) by 512 thr
      const f16x8* Kt = (const f16x8*)(Kbh + (size_t)t * (128 * 256));
      #pragma unroll
      for (int s2 = 0; s2 < 4; ++s2) {
        int gidx = tid + s2 * 512;
        int kk = gidx >> 4, rem = gidx & 15;
        int pp = rem >> 3,  cc  = rem & 7;
        f16x8 v = Kt[gidx];
        *(f16x8*)(smem + pp * 16384 + ((kk * 8 + (cc ^ (kk & 7))) << 4)) = v;
      }
    }
    __syncthreads();
    {
      int keyr = wid * 16 + m;
      int s0 = ( g      ^ (m & 7));
      int s1 = ((4 + g) ^ (m & 7));
      f16x8 b_hi0 = ((const f16x8*)smem)[keyr * 8 + s0];
      f16x8 b_hi1 = ((const f16x8*)smem)[keyr * 8 + s1];
      f16x8 b_lo0 = ((const f16x8*)(smem + 16384))[keyr * 8 + s0];
      f16x8 b_lo1 = ((const f16x8*)(smem + 16384))[keyr * 8 + s1];
      f32x4 acc = {0.f, 0.f, 0.f, 0.f};
      acc = __builtin_amdgcn_mfma_f32_16x16x32_f16(a_hi0, b_hi0, acc, 0, 0, 0);
      acc = __builtin_amdgcn_mfma_f32_16x16x32_f16(a_hi1, b_hi1, acc, 0, 0, 0);
      acc = __builtin_amdgcn_mfma_f32_16x16x32_f16(a_hi0, b_lo0, acc, 0, 0, 0);
      acc = __builtin_amdgcn_mfma_f32_16x16x32_f16(a_hi1, b_lo1, acc, 0, 0, 0);
      acc = __builtin_amdgcn_mfma_f32_16x16x32_f16(a_lo0, b_hi0, acc, 0, 0, 0);
      acc = __builtin_amdgcn_mfma_f32_16x16x32_f16(a_lo1, b_hi1, acc, 0, 0, 0);
      acc = __builtin_amdgcn_mfma_f32_16x16x32_f16(a_lo0, b_lo0, acc, 0, 0, 0);
      acc = __builtin_amdgcn_mfma_f32_16x16x32_f16(a_lo1, b_lo1, acc, 0, 0, 0);
      sreg[t] = acc * 0.125f;
    }
    __syncthreads();
  }

  // ---- per-row max/min (deterministic shfl-group + partials) ----
  float lmax[4], lmin[4];
  #pragma unroll
  for (int rg = 0; rg < 4; ++rg) { lmax[rg] = -INFINITY; lmin[rg] = INFINITY; }
  #pragma unroll
  for (int t = 0; t < 16; ++t)
    #pragma unroll
    for (int rg = 0; rg < 4; ++rg) {
      float v = sreg[t][rg];
      lmax[rg] = fmaxf(lmax[rg], v); lmin[rg] = fminf(lmin[rg], v);
    }
  #pragma unroll
  for (int off = 8; off >= 1; off >>= 1)
    #pragma unroll
    for (int rg = 0; rg < 4; ++rg) {
      lmax[rg] = fmaxf(lmax[rg], __shfl_xor(lmax[rg], off));
      lmin[rg] = fminf(lmin[rg], __shfl_xor(lmin[rg], off));
    }
  if (m == 0)
    #pragma unroll
    for (int rg = 0; rg < 4; ++rg) {
      pmax[wid * 16 + g * 4 + rg] = lmax[rg];
      pmin[wid * 16 + g * 4 + rg] = lmin[rg];
    }
  {
    unsigned* h32 = (unsigned*)smem;   // clear hist (K-stage dead)
    #pragma unroll
    for (int i = 0; i < 16; ++i) h32[tid + i * 512] = 0u;
  }
  __syncthreads();
  if (wid == 0 && lane < 16) {
    float mx = -INFINITY, mn = INFINITY;
    for (int w = 0; w < 8; ++w) {
      mx = fmaxf(mx, pmax[w * 16 + lane]);
      mn = fminf(mn, pmin[w * 16 + lane]);
    }
    rmax[lane] = mx; rmin[lane] = mn;
  }
  __syncthreads();

  // ---- histogram (transposed bins per row) ----
  if (nk > 0) {
    #pragma unroll
    for (int rg = 0; rg < 4; ++rg) {
      int r = g * 4 + rg;
      float vmx = rmax[r], vmn = rmin[r];
      float range = vmx - vmn;
      float scale = (range > 0.f) ? ((float)NBINS / range) : 0.f;
      float boff  = vmn * scale;
      #pragma unroll
      for (int t = 0; t < 16; ++t) {
        int bb = (int)fmaf(sreg[t][rg], scale, -boff);
        bb = bb < 0 ? 0 : (bb > NBINS - 1 ? NBINS - 1 : bb);
        atomicAdd(&hist[r * 512 + (((bb & 7) << 6) | (bb >> 3))], 1u);
      }
    }
  }
  __syncthreads();

  // ---- scan (wave w -> rows 2w, 2w+1) ----
  for (int rr = 0; rr < 2; ++rr) {
    int row = wid * 2 + rr;
    if (lane == 0) ccnt[row] = 0u;
    if (nk > 0) {
      unsigned* hw = hist + row * 512;
      unsigned A = 0;
      #pragma unroll
      for (int i2 = 0; i2 < BPL; ++i2) A += hw[(i2 << 6) | lane];
      unsigned ssum = A;
      #pragma unroll
      for (int off = 1; off <= 32; off <<= 1) {
        unsigned u = (unsigned)__shfl_down((int)ssum, off);
        if (lane + off < 64) ssum += u;
      }
      unsigned cum = ssum - A;
      int bsel = -1; int mloc = 0; int nbloc = 0;
      #pragma unroll
      for (int i2 = BPL - 1; i2 >= 0; --i2) {
        unsigned c0 = cum; cum += hw[(i2 << 6) | lane];
        if (bsel < 0 && c0 < (unsigned)nk && cum >= (unsigned)nk) {
          bsel = (lane << 3) | i2; mloc = nk - (int)c0; nbloc = (int)(cum - c0);
        }
      }
      unsigned long long fmk = __ballot(bsel >= 0);
      int srcl = __ffsll(fmk) - 1;
      bsel = __shfl(bsel, srcl);
      mloc = __shfl(mloc, srcl);
      nbloc = __shfl(nbloc, srcl);
      if (lane == 0) { bselA[row] = bsel; mthA[row] = mloc; nbinA[row] = nbloc; }
    } else {
      if (lane == 0) thrA[row] = -INFINITY;
    }
  }
  __syncthreads();

  // ---- candidate collection (crossing bin) ----
  if (nk > 0) {
    #pragma unroll
    for (int rg = 0; rg < 4; ++rg) {
      int r = g * 4 + rg;
      int bs = bselA[r];
      if (nbinA[r] <= CANDMAX) {
        float vmx = rmax[r], vmn = rmin[r];
        float range = vmx - vmn;
        float scale = (range > 0.f) ? ((float)NBINS / range) : 0.f;
        float boff  = vmn * scale;
        #pragma unroll
        for (int t = 0; t < 16; ++t) {
          float v = sreg[t][rg];
          int bb = (int)fmaf(v, scale, -boff);
          bb = bb < 0 ? 0 : (bb > NBINS - 1 ? NBINS - 1 : bb);
          if (bb == bs) {
            unsigned ix = atomicAdd(&ccnt[r], 1u);
            if (ix < CANDMAX) cand[r * CANDMAX + ix] = v;
          }
        }
      }
    }
  }
  __syncthreads();

  // ---- m-th largest within bin (duplicate-aware, order-invariant) ----
  if (nk > 0) {
    for (int rr = 0; rr < 2; ++rr) {
      int row = wid * 2 + rr;
      int nb = nbinA[row], mth = mthA[row];
      float th;
      if (nb <= CANDMAX) {
        const float* cw = cand + row * CANDMAX;
        float prev = INFINITY, kth = -INFINITY;
        int got = 0, guard = 0;
        while (got < mth && guard++ <= CANDMAX) {
          float best = -INFINITY;
          for (int i = 0; i < nb; ++i) {
            float v = cw[i];
            if (v < prev && v > best) best = v;
          }
          int ce = 0;
          for (int i = 0; i < nb; ++i) if (cw[i] == best) ce++;
          got += ce; prev = best; kth = best;
        }
        th = kth;
      } else {
        // statistically-never (freak tie mass); bin lower edge keeps all ties
        float vmx = rmax[row], vmn = rmin[row];
        th = vmn + (float)bselA[row] * ((vmx - vmn) * (1.0f / (float)NBINS));
      }
      if (lane == 0) thrA[row] = th;
    }
  }
  __syncthreads();

  // ---- P write (fp16, full 16x2048, swizzled) + psum ----
  float lsum[4] = {0.f, 0.f, 0.f, 0.f};
  #pragma unroll
  for (int rg = 0; rg < 4; ++rg) {
    int r = g * 4 + rg;
    float th = thrA[r], vmx = rmax[r];
    int swz = (r & 7) << 4;
    #pragma unroll
    for (int t = 0; t < 16; ++t) {
      float v = sreg[t][rg];
      float p = (v >= th) ? __expf(v - vmx) : 0.f;
      lsum[rg] += p;
      int col = t * 128 + wid * 16 + m;
      *(_Float16*)(smem + ((r * 4096 + col * 2) ^ swz)) = (_Float16)p;
    }
  }
  #pragma unroll
  for (int off = 8; off >= 1; off >>= 1)
    #pragma unroll
    for (int rg = 0; rg < 4; ++rg) lsum[rg] += __shfl_xor(lsum[rg], off);
  if (m == 0)
    #pragma unroll
    for (int rg = 0; rg < 4; ++rg) psp[wid * 16 + g * 4 + rg] = lsum[rg];
  __syncthreads();
  if (wid == 0 && lane < 16) {
    float s = 0.f;
    for (int w = 0; w < 8; ++w) s += psp[w * 16 + lane];
    psumA[lane] = s;
  }
  __syncthreads();

  // ---- PV via MFMA (R11-verified layout) ----
  const int dg = wid & 3;
  const int kh = wid >> 2;
  const int swzA = (m & 7) << 4;
  const _Float16* VTb = VT + (size_t)bh * (DHEAD * S_LEN);
  f32x4 acc = {0.f, 0.f, 0.f, 0.f};
  #pragma unroll
  for (int kt = 0; kt < 8; ++kt) {
    #pragma unroll
    for (int s = 0; s < 4; ++s) {
      f16x8 af = *(const f16x8*)(smem +
          ((m * 4096 + kt * 512 + kh * 256 + s * 64 + g * 16) ^ swzA));
      f16x8 bf = *(const f16x8*)(VTb + (size_t)(dg * 16 + m) * S_LEN +
                                 kt * 256 + kh * 128 + s * 32 + g * 8);
      acc = __builtin_amdgcn_mfma_f32_16x16x32_f16(af, bf, acc, 0, 0, 0);
    }
  }
  if (kh == 1)
    redS[dg * 64 + lane] = make_float4(acc[0], acc[1], acc[2], acc[3]);
  __syncthreads();
  if (kh == 0) {
    float4 o = redS[dg * 64 + lane];
    float ov[4] = {o.x, o.y, o.z, o.w};
    #pragma unroll
    for (int rg = 0; rg < 4; ++rg) {
      int row = g * 4 + rg;
      float val = (acc[rg] + ov[rg]) / psumA[row];
      Out[(size_t)(rowb + row) * DHEAD + dg * 16 + m] = val;
    }
  }
}

// ---------------------------------------------------------------------------
// Fallback monolithic kernel (round-3, proven) for tiny ws_size
// ---------------------------------------------------------------------------
#define TQ 16
#define KT 128
#define NTILES (S_LEN / KT)
#define THREADS 512
#define LCAP 256
#define SOFF   0
#define KHI    131072
#define KLO    147456
#define HOFF   131072
#define KLOFF  147456
#define PLOFF  155648

__global__ __launch_bounds__(THREADS, 2)
void dpsa_kernel(const float* __restrict__ Q, const float* __restrict__ K,
                 const float* __restrict__ V, const int* __restrict__ nkp,
                 float* __restrict__ Out) {
  __shared__ __align__(16) char smem[163840];
  float* Sf = (float*)(smem + SOFF);

  const int tid  = (int)threadIdx.x;
  const int lane = tid & 63;
  const int wid  = tid >> 6;
  const int bid  = (int)blockIdx.x;
  const int bh   = bid >> 7;
  const int qblk = bid & 127;
  const size_t base = (size_t)bh * (size_t)(S_LEN * DHEAD);
  const float* Kbh = K + base;
  const float* Vbh = V + base;

  int nk = nkp[0];
  if (nk > S_LEN) nk = S_LEN;

  const int g = lane >> 4;
  const int m = lane & 15;

  f16x8 a_hi0, a_lo0, a_hi1, a_lo1;
  {
    const float* Qrow = Q + base + (size_t)(qblk * TQ + m) * DHEAD;
    float4 qa = *(const float4*)(Qrow + g * 8);
    float4 qb = *(const float4*)(Qrow + g * 8 + 4);
    float4 qc = *(const float4*)(Qrow + 32 + g * 8);
    float4 qd = *(const float4*)(Qrow + 32 + g * 8 + 4);
    float x[16] = {qa.x,qa.y,qa.z,qa.w, qb.x,qb.y,qb.z,qb.w,
                   qc.x,qc.y,qc.z,qc.w, qd.x,qd.y,qd.z,qd.w};
    #pragma unroll
    for (int j = 0; j < 8; ++j) {
      _Float16 h0 = (_Float16)x[j];
      a_hi0[j] = h0;  a_lo0[j] = (_Float16)(x[j] - (float)h0);
      _Float16 h1 = (_Float16)x[8 + j];
      a_hi1[j] = h1;  a_lo1[j] = (_Float16)(x[8 + j] - (float)h1);
    }
  }

  const f16x8* Kh = (const f16x8*)(smem + KHI);
  const f16x8* Kl = (const f16x8*)(smem + KLO);
  const int keyl = tid >> 2;
  const int q4i  = tid & 3;
  const int sw   = keyl & 7;

  float4 pf0, pf1, pf2, pf3;
  {
    const float4* Kg4 = (const float4*)Kbh;
    int idx = keyl * 16 + q4i * 4;
    pf0 = Kg4[idx]; pf1 = Kg4[idx + 1]; pf2 = Kg4[idx + 2]; pf3 = Kg4[idx + 3];
  }

  for (int t = 0; t < NTILES; ++t) {
    {
      float x[16] = {pf0.x,pf0.y,pf0.z,pf0.w, pf1.x,pf1.y,pf1.z,pf1.w,
                     pf2.x,pf2.y,pf2.z,pf2.w, pf3.x,pf3.y,pf3.z,pf3.w};
      f16x8 hi0, hi1, lo0, lo1;
      #pragma unroll
      for (int j = 0; j < 8; ++j) {
        _Float16 h0 = (_Float16)x[j];
        hi0[j] = h0;  lo0[j] = (_Float16)(x[j] - (float)h0);
        _Float16 h1 = (_Float16)x[8 + j];
        hi1[j] = h1;  lo1[j] = (_Float16)(x[8 + j] - (float)h1);
      }
      f16x8* KhwF = (f16x8*)(smem + KHI);
      f16x8* KlwF = (f16x8*)(smem + KLO);
      KhwF[keyl * 8 + ((q4i * 2)     ^ sw)] = hi0;
      KhwF[keyl * 8 + ((q4i * 2 + 1) ^ sw)] = hi1;
      KlwF[keyl * 8 + ((q4i * 2)     ^ sw)] = lo0;
      KlwF[keyl * 8 + ((q4i * 2 + 1) ^ sw)] = lo1;
    }
    if (t + 1 < NTILES) {
      const float4* Kg4 = (const float4*)(Kbh + (size_t)(t + 1) * (KT * DHEAD));
      int idx = keyl * 16 + q4i * 4;
      pf0 = Kg4[idx]; pf1 = Kg4[idx + 1]; pf2 = Kg4[idx + 2]; pf3 = Kg4[idx + 3];
    }
    __syncthreads();
    {
      int keyr = wid * 16 + m;
      int s0 = ( g      ^ (m & 7));
      int s1 = ((4 + g) ^ (m & 7));
      f16x8 b_hi0 = Kh[keyr * 8 + s0];
      f16x8 b_hi1 = Kh[keyr * 8 + s1];
      f16x8 b_lo0 = Kl[keyr * 8 + s0];
      f16x8 b_lo1 = Kl[keyr * 8 + s1];
      f32x4 acc = {0.f, 0.f, 0.f, 0.f};
      acc = __builtin_amdgcn_mfma_f32_16x16x32_f16(a_hi0, b_hi0, acc, 0, 0, 0);
      acc = __builtin_amdgcn_mfma_f32_16x16x32_f16(a_hi1, b_hi1, acc, 0, 0, 0);
      acc = __builtin_amdgcn_mfma_f32_16x16x32_f16(a_hi0, b_lo0, acc, 0, 0, 0);
      acc = __builtin_amdgcn_mfma_f32_16x16x32_f16(a_hi1, b_lo1, acc, 0, 0, 0);
      acc = __builtin_amdgcn_mfma_f32_16x16x32_f16(a_lo0, b_hi0, acc, 0, 0, 0);
      acc = __builtin_amdgcn_mfma_f32_16x16x32_f16(a_lo1, b_hi1, acc, 0, 0, 0);
      int keyabs = t * KT + wid * 16 + m;
      #pragma unroll
      for (int rg = 0; rg < 4; ++rg)
        Sf[(size_t)(g * 4 + rg) * S_LEN + keyabs] = acc[rg] * 0.125f;
    }
    __syncthreads();
  }

  unsigned* hw = (unsigned*)(smem + HOFF)  + wid * NBINS;
  unsigned* kl = (unsigned*)(smem + KLOFF) + wid * LCAP;
  float*    pl = (float*)(smem + PLOFF)    + wid * LCAP;
  const float4* S4 = (const float4*)(smem + SOFF);

  for (int rr = 0; rr < 2; ++rr) {
    const int row = wid * 2 + rr;
    float sarr[32];
    #pragma unroll
    for (int j = 0; j < 8; ++j) {
      float4 v4 = S4[row * (S_LEN / 4) + j * 64 + lane];
      sarr[j*4+0] = v4.x; sarr[j*4+1] = v4.y;
      sarr[j*4+2] = v4.z; sarr[j*4+3] = v4.w;
    }

    float vmax = -INFINITY, vmin = INFINITY;
    #pragma unroll
    for (int q = 0; q < 32; ++q) {
      vmax = fmaxf(vmax, sarr[q]); vmin = fminf(vmin, sarr[q]);
    }
    #pragma unroll
    for (int off = 32; off >= 1; off >>= 1) {
      vmax = fmaxf(vmax, __shfl_xor(vmax, off));
      vmin = fminf(vmin, __shfl_xor(vmin, off));
    }

    float thresh = -INFINITY;
    if (nk > 0) {
      float range = vmax - vmin;
      float scale = (range > 0.f) ? ((float)NBINS / range) : 0.f;
      #pragma unroll
      for (int i2 = 0; i2 < BPL; ++i2) hw[(i2 << 6) | lane] = 0u;
      #pragma unroll
      for (int q = 0; q < 32; ++q) {
        int bb = (int)((sarr[q] - vmin) * scale);
        bb = bb < 0 ? 0 : (bb > NBINS - 1 ? NBINS - 1 : bb);
        atomicAdd(&hw[((bb & 7) << 6) | (bb >> 3)], 1u);
      }
      unsigned A = 0; unsigned hv[BPL];
      #pragma unroll
      for (int i2 = 0; i2 < BPL; ++i2) { hv[i2] = hw[(i2 << 6) | lane]; A += hv[i2]; }
      unsigned ssum = A;
      #pragma unroll
      for (int off = 1; off <= 32; off <<= 1) {
        unsigned u = (unsigned)__shfl_down((int)ssum, off);
        if (lane + off < 64) ssum += u;
      }
      unsigned cum = ssum - A;
      int bsel = -1; int mloc = 0;
      #pragma unroll
      for (int i2 = BPL - 1; i2 >= 0; --i2) {
        unsigned c0 = cum; cum += hv[i2];
        if (bsel < 0 && c0 < (unsigned)nk && cum >= (unsigned)nk) {
          bsel = (lane << 3) | i2; mloc = nk - (int)c0;
        }
      }
      unsigned long long fmk = __ballot(bsel >= 0);
      int srcl = __ffsll(fmk) - 1;
      bsel = __shfl(bsel, srcl);
      int mth = __shfl(mloc, srcl);

      unsigned inbin = 0;
      #pragma unroll
      for (int q = 0; q < 32; ++q) {
        int bb = (int)((sarr[q] - vmin) * scale);
        bb = bb < 0 ? 0 : (bb > NBINS - 1 ? NBINS - 1 : bb);
        if (bb == bsel) inbin |= (1u << q);
      }
      while (true) {
        float cmax = -INFINITY;
        #pragma unroll
        for (int q = 0; q < 32; ++q) if (inbin & (1u << q)) cmax = fmaxf(cmax, sarr[q]);
        #pragma unroll
        for (int off = 32; off >= 1; off >>= 1) cmax = fmaxf(cmax, __shfl_xor(cmax, off));
        int cnt = 0;
        #pragma unroll
        for (int q = 0; q < 32; ++q) if ((inbin & (1u << q)) && sarr[q] == cmax) cnt++;
        #pragma unroll
        for (int off = 32; off >= 1; off >>= 1) cnt += __shfl_xor(cnt, off);
        if (mth <= cnt) { thresh = cmax; break; }
        mth -= cnt;
        #pragma unroll
        for (int q = 0; q < 32; ++q) if ((inbin & (1u << q)) && sarr[q] == cmax) inbin &= ~(1u << q);
      }
    }

    float psum = 0.f;
    #pragma unroll
    for (int q = 0; q < 32; ++q) {
      float p = (sarr[q] >= thresh) ? expf(sarr[q] - vmax) : 0.f;
      sarr[q] = p; psum += p;
    }
    #pragma unroll
    for (int off = 32; off >= 1; off >>= 1) psum += __shfl_xor(psum, off);

    unsigned nkept = 0;
    #pragma unroll
    for (int q = 0; q < 32; ++q) {
      bool keep = sarr[q] > 0.f;
      unsigned long long mk = __ballot(keep);
      if (keep) {
        unsigned idx = nkept + (unsigned)__popcll(mk & ((1ull << lane) - 1ull));
        if (idx < LCAP) {
          kl[idx] = (unsigned)((q >> 2) * 256 + lane * 4 + (q & 3));
          pl[idx] = sarr[q];
        }
      }
      nkept += (unsigned)__popcll(mk);
    }

    float acc0 = 0.f, acc1 = 0.f, acc2 = 0.f, acc3 = 0.f;
    if (nkept <= LCAP) {
      unsigned i = 0;
      for (; i + 4 <= nkept; i += 4) {
        acc0 = fmaf(pl[i+0], Vbh[(size_t)kl[i+0] * DHEAD + lane], acc0);
        acc1 = fmaf(pl[i+1], Vbh[(size_t)kl[i+1] * DHEAD + lane], acc1);
        acc2 = fmaf(pl[i+2], Vbh[(size_t)kl[i+2] * DHEAD + lane], acc2);
        acc3 = fmaf(pl[i+3], Vbh[(size_t)kl[i+3] * DHEAD + lane], acc3);
      }
      for (; i < nkept; ++i)
        acc0 = fmaf(pl[i], Vbh[(size_t)kl[i] * DHEAD + lane], acc0);
    } else {
      #pragma unroll
      for (int q = 0; q < 32; ++q) {
        for (int sl = 0; sl < 64; ++sl) {
          float pp = __shfl(sarr[q], sl);
          if (pp > 0.f)
            acc0 = fmaf(pp, Vbh[(size_t)((q >> 2) * 256 + sl * 4 + (q & 3)) * DHEAD + lane], acc0);
        }
      }
    }
    float accv = (acc0 + acc1) + (acc2 + acc3);
    Out[base + (size_t)(qblk * TQ + row) * DHEAD + lane] = accv / psum;
  }
}

extern "C" void kernel_launch(void* const* d_in, const int* in_sizes, int n_in,
                              void* d_out, int out_size, void* d_ws, size_t ws_size,
                              hipStream_t stream) {
  const float* q  = (const float*)d_in[0];
  const float* k  = (const float*)d_in[1];
  const float* v  = (const float*)d_in[2];
  const int*   nk = (const int*)d_in[3];
  float* out = (float*)d_out;

  if (ws_size >= WS_NEED) {
    _Float16* vt  = (_Float16*)d_ws;
    char*     khl = (char*)d_ws + VT_BYTES;
    prep_khl<<<dim3(4096), dim3(256), 0, stream>>>(k, khl);
    prep_vt<<<dim3(512), dim3(256), 0, stream>>>(v, vt);
    fused_kernel<<<dim3(NROWS / 16), dim3(512), 0, stream>>>(q, khl, vt, nk, out);
  } else {
    dpsa_kernel<<<dim3(8192), dim3(THREADS), 0, stream>>>(q, k, v, nk, out);
  }
}

// Round 16
// 901.955 us; speedup vs baseline: 1.3091x; 1.3091x over previous
//
#include <hip/hip_runtime.h>
#include <math.h>

#define S_LEN 2048
#define DHEAD 64
#define NBINS 512
#define BPL (NBINS / 64)
#define CANDMAX 48
#define NBH 64
#define NROWS (NBH * S_LEN)                 // 32768
#define VT_BYTES (64ull * DHEAD * S_LEN * 2)  // 16 MB fp16 V^T

typedef _Float16 f16x8 __attribute__((ext_vector_type(8)));
typedef _Float16 f16x4 __attribute__((ext_vector_type(4)));
typedef float    f32x4 __attribute__((ext_vector_type(4)));

// ---------------------------------------------------------------------------
// Kernel P: V fp32 -> V^T fp16  (VT[bh][dim][key]); one-time, L2-served later.
// ---------------------------------------------------------------------------
__global__ __launch_bounds__(256)
void prep_vt(const float* __restrict__ V, _Float16* __restrict__ VT) {
  const int bh  = (int)blockIdx.x >> 3;
  const int dg8 = (int)blockIdx.x & 7;          // dims dg8*8 .. +7
  const int t   = (int)threadIdx.x;
  const int dim = dg8 * 8 + (t >> 5);
  const int kc  = t & 31;
  const float* Vb = V + (size_t)bh * (S_LEN * DHEAD);
  _Float16* VTb = VT + ((size_t)bh * DHEAD + dim) * S_LEN;
  for (int i = 0; i < 8; ++i) {
    int key0 = (kc + i * 32) * 8;
    f16x8 h;
    #pragma unroll
    for (int j = 0; j < 8; ++j)
      h[j] = (_Float16)Vb[(size_t)(key0 + j) * DHEAD + dim];
    *(f16x8*)(VTb + key0) = h;                  // coalesced 16B x 32 lanes
  }
}

// ---------------------------------------------------------------------------
// Kernel A: QK^T via 4-term hi/lo fp16 MFMA. XCD-swizzled.
// Block = 256 thr (4 waves) = 64 q-rows x 256 keys (key eighth kb=0..7).
// Grid = rows/8 -> 4 blocks/CU.
// ---------------------------------------------------------------------------
__global__ __launch_bounds__(256, 4)
void qk_kernel(const float* __restrict__ Q, const float* __restrict__ K,
               float* __restrict__ Sws, int row0) {
  __shared__ __align__(16) char kbuf[32768];   // hi 16KB | lo 16KB
  f16x8* Khw = (f16x8*)kbuf;
  f16x8* Klw = (f16x8*)(kbuf + 16384);

  const int tid  = (int)threadIdx.x;
  const int lane = tid & 63;
  const int wid  = tid >> 6;
  const int nxl  = (int)gridDim.x >> 3;         // blocks per XCD
  const int xcd  = (int)blockIdx.x & 7;
  const int lb   = (int)blockIdx.x >> 3;
  const int rb   = lb >> 3;
  const int kb   = lb & 7;                      // key eighth
  const int rowl = xcd * (nxl * 8) + rb * 64 + wid * 16;  // chunk-local
  const int rowg = row0 + rowl;
  const int bh   = rowg >> 11;
  const int key0 = kb * 256;

  const int g = lane >> 4;
  const int m = lane & 15;

  f16x8 a_hi0, a_lo0, a_hi1, a_lo1;
  {
    const float* Qrow = Q + (size_t)(rowg + m) * DHEAD;
    float4 qa = *(const float4*)(Qrow + g * 8);
    float4 qb = *(const float4*)(Qrow + g * 8 + 4);
    float4 qc = *(const float4*)(Qrow + 32 + g * 8);
    float4 qd = *(const float4*)(Qrow + 32 + g * 8 + 4);
    float x[16] = {qa.x,qa.y,qa.z,qa.w, qb.x,qb.y,qb.z,qb.w,
                   qc.x,qc.y,qc.z,qc.w, qd.x,qd.y,qd.z,qd.w};
    #pragma unroll
    for (int j = 0; j < 8; ++j) {
      _Float16 h0 = (_Float16)x[j];
      a_hi0[j] = h0;  a_lo0[j] = (_Float16)(x[j] - (float)h0);
      _Float16 h1 = (_Float16)x[8 + j];
      a_hi1[j] = h1;  a_lo1[j] = (_Float16)(x[8 + j] - (float)h1);
    }
  }

  const float* Kb = K + (size_t)bh * (S_LEN * DHEAD);
  float* Srow = Sws + (size_t)rowl * S_LEN;

  const int skey  = tid >> 1;       // staging: key 0..127
  const int shalf = tid & 1;        // d half
  const int ssw   = skey & 7;

  float4 pf[8];
  {
    const float4* kr = (const float4*)(Kb + (size_t)(key0 + skey) * DHEAD + shalf * 32);
    #pragma unroll
    for (int j = 0; j < 8; ++j) pf[j] = kr[j];
  }

  #pragma unroll
  for (int t = 0; t < 2; ++t) {
    #pragma unroll
    for (int jj = 0; jj < 4; ++jj) {
      float x[8] = {pf[2*jj].x, pf[2*jj].y, pf[2*jj].z, pf[2*jj].w,
                    pf[2*jj+1].x, pf[2*jj+1].y, pf[2*jj+1].z, pf[2*jj+1].w};
      f16x8 hi, lo;
      #pragma unroll
      for (int j = 0; j < 8; ++j) {
        _Float16 h = (_Float16)x[j];
        hi[j] = h;
        lo[j] = (_Float16)(x[j] - (float)h);
      }
      int c = shalf * 4 + jj;
      Khw[skey * 8 + (c ^ ssw)] = hi;
      Klw[skey * 8 + (c ^ ssw)] = lo;
    }
    if (t + 1 < 2) {
      const float4* kr = (const float4*)(Kb + (size_t)(key0 + 128 + skey) * DHEAD + shalf * 32);
      #pragma unroll
      for (int j = 0; j < 8; ++j) pf[j] = kr[j];
    }
    __syncthreads();

    const f16x8* Kh = (const f16x8*)kbuf;
    const f16x8* Kl = (const f16x8*)(kbuf + 16384);
    int slot0 = ( g      ^ (m & 7));
    int slot1 = ((4 + g) ^ (m & 7));
    #pragma unroll
    for (int p = 0; p < 8; ++p) {
      int keyr = p * 16 + m;
      f16x8 b_hi0 = Kh[keyr * 8 + slot0];
      f16x8 b_hi1 = Kh[keyr * 8 + slot1];
      f16x8 b_lo0 = Kl[keyr * 8 + slot0];
      f16x8 b_lo1 = Kl[keyr * 8 + slot1];
      f32x4 acc = {0.f, 0.f, 0.f, 0.f};
      acc = __builtin_amdgcn_mfma_f32_16x16x32_f16(a_hi0, b_hi0, acc, 0, 0, 0);
      acc = __builtin_amdgcn_mfma_f32_16x16x32_f16(a_hi1, b_hi1, acc, 0, 0, 0);
      acc = __builtin_amdgcn_mfma_f32_16x16x32_f16(a_hi0, b_lo0, acc, 0, 0, 0);
      acc = __builtin_amdgcn_mfma_f32_16x16x32_f16(a_hi1, b_lo1, acc, 0, 0, 0);
      acc = __builtin_amdgcn_mfma_f32_16x16x32_f16(a_lo0, b_hi0, acc, 0, 0, 0);
      acc = __builtin_amdgcn_mfma_f32_16x16x32_f16(a_lo1, b_hi1, acc, 0, 0, 0);
      acc = __builtin_amdgcn_mfma_f32_16x16x32_f16(a_lo0, b_lo0, acc, 0, 0, 0);
      acc = __builtin_amdgcn_mfma_f32_16x16x32_f16(a_lo1, b_lo1, acc, 0, 0, 0);
      int col = key0 + t * 128 + p * 16 + m;
      #pragma unroll
      for (int rg = 0; rg < 4; ++rg)
        __builtin_nontemporal_store(acc[rg] * 0.125f,
            &Srow[(size_t)(g * 4 + rg) * S_LEN + col]);
    }
    __syncthreads();
  }
}

// ---------------------------------------------------------------------------
// Kernel B (R10-proven): selection (register sarr, per-wave) + MFMA masked-PV.
// 512 thr = 8 waves; wave w selects rows 2w,2w+1; per-kt P subtile + 4 MFMA.
// ---------------------------------------------------------------------------
__global__ __launch_bounds__(512, 4)
void selmm_kernel(const float* __restrict__ Sws, const _Float16* __restrict__ VT,
                  const int* __restrict__ nkp, float* __restrict__ Out, int row0) {
  __shared__ unsigned histS[8][NBINS];                 // 16 KB
  __shared__ float candS[8][CANDMAX];                  // 1.5 KB
  __shared__ unsigned candCnt[8];
  __shared__ float psumS[16];
  __shared__ __align__(16) char pbuf[8192];            // P tile: 16 rows x 512B
  __shared__ __align__(16) float4 redS[4][64];         // 4 KB kh-reduction

  const int tid  = (int)threadIdx.x;
  const int lane = tid & 63;
  const int wid  = tid >> 6;                           // 0..7
  const int nxl  = (int)gridDim.x >> 3;
  const int xcd  = (int)blockIdx.x & 7;
  const int lbk  = (int)blockIdx.x >> 3;
  const int rowlb = xcd * (nxl * 16) + lbk * 16;       // chunk-local base
  const int rowgb = row0 + rowlb;                      // global base (16-aligned)
  const int bh    = rowgb >> 11;

  int nk = nkp[0];
  if (nk > S_LEN) nk = S_LEN;

  unsigned* hw = histS[wid];
  float sarr[2][32];
  float thr2[2], vmx2[2];

  // ---------------- phase 1: per-wave selection for rows 2w, 2w+1 ----------
  #pragma unroll
  for (int rr = 0; rr < 2; ++rr) {
    const int rloc = wid * 2 + rr;
    {
      const f32x4* S4 = (const f32x4*)(Sws + (size_t)(rowlb + rloc) * S_LEN);
      #pragma unroll
      for (int j = 0; j < 8; ++j) {
        f32x4 v4 = __builtin_nontemporal_load(S4 + j * 64 + lane);
        sarr[rr][j*4+0] = v4[0]; sarr[rr][j*4+1] = v4[1];
        sarr[rr][j*4+2] = v4[2]; sarr[rr][j*4+3] = v4[3];
      }
    }

    float vmax = -INFINITY, vmin = INFINITY;
    #pragma unroll
    for (int q = 0; q < 32; ++q) {
      vmax = fmaxf(vmax, sarr[rr][q]); vmin = fminf(vmin, sarr[rr][q]);
    }
    #pragma unroll
    for (int off = 32; off >= 1; off >>= 1) {
      vmax = fmaxf(vmax, __shfl_xor(vmax, off));
      vmin = fminf(vmin, __shfl_xor(vmin, off));
    }

    float thresh = -INFINITY;
    if (nk > 0) {
      float range = vmax - vmin;
      float scale = (range > 0.f) ? ((float)NBINS / range) : 0.f;
      float boff  = vmin * scale;

      #pragma unroll
      for (int i2 = 0; i2 < BPL; ++i2) hw[(i2 << 6) | lane] = 0u;
      #pragma unroll
      for (int q = 0; q < 32; ++q) {
        int bb = (int)fmaf(sarr[rr][q], scale, -boff);
        bb = bb < 0 ? 0 : (bb > NBINS - 1 ? NBINS - 1 : bb);
        atomicAdd(&hw[((bb & 7) << 6) | (bb >> 3)], 1u);     // transposed bins
      }

      unsigned A = 0;
      #pragma unroll
      for (int i2 = 0; i2 < BPL; ++i2) A += hw[(i2 << 6) | lane];
      unsigned ssum = A;
      #pragma unroll
      for (int off = 1; off <= 32; off <<= 1) {
        unsigned u = (unsigned)__shfl_down((int)ssum, off);
        if (lane + off < 64) ssum += u;
      }
      unsigned cum = ssum - A;
      int bsel = -1; int mloc = 0; int nbloc = 0;
      #pragma unroll
      for (int i2 = BPL - 1; i2 >= 0; --i2) {
        unsigned c0 = cum; cum += hw[(i2 << 6) | lane];
        if (bsel < 0 && c0 < (unsigned)nk && cum >= (unsigned)nk) {
          bsel = (lane << 3) | i2; mloc = nk - (int)c0; nbloc = (int)(cum - c0);
        }
      }
      unsigned long long fm = __ballot(bsel >= 0);
      int srcl = __ffsll(fm) - 1;
      bsel = __shfl(bsel, srcl);
      int mth  = __shfl(mloc, srcl);
      int nbin = __shfl(nbloc, srcl);

      if (nbin <= CANDMAX) {
        if (lane == 0) candCnt[wid] = 0u;
        __builtin_amdgcn_wave_barrier();
        #pragma unroll
        for (int q = 0; q < 32; ++q) {
          int bb = (int)fmaf(sarr[rr][q], scale, -boff);
          bb = bb < 0 ? 0 : (bb > NBINS - 1 ? NBINS - 1 : bb);
          if (bb == bsel) {
            unsigned ix = atomicAdd(&candCnt[wid], 1u);
            if (ix < CANDMAX) candS[wid][ix] = sarr[rr][q];
          }
        }
        __builtin_amdgcn_wave_barrier();
        float prev = INFINITY, kth = -INFINITY;
        int got = 0, guard = 0;
        while (got < mth && guard++ <= CANDMAX) {
          float best = -INFINITY;
          for (int i = 0; i < nbin; ++i) {
            float v = candS[wid][i];
            if (v < prev && v > best) best = v;
          }
          int ce = 0;
          for (int i = 0; i < nbin; ++i) if (candS[wid][i] == best) ce++;
          got += ce; prev = best; kth = best;
        }
        thresh = kth;
      } else {
        // exact shfl-chain fallback (pathological tie mass)
        unsigned inbin = 0;
        #pragma unroll
        for (int q = 0; q < 32; ++q) {
          int bb = (int)fmaf(sarr[rr][q], scale, -boff);
          bb = bb < 0 ? 0 : (bb > NBINS - 1 ? NBINS - 1 : bb);
          if (bb == bsel) inbin |= (1u << q);
        }
        while (true) {
          float cmax = -INFINITY;
          #pragma unroll
          for (int q = 0; q < 32; ++q) if (inbin & (1u << q)) cmax = fmaxf(cmax, sarr[rr][q]);
          #pragma unroll
          for (int off = 32; off >= 1; off >>= 1) cmax = fmaxf(cmax, __shfl_xor(cmax, off));
          int cnt = 0;
          #pragma unroll
          for (int q = 0; q < 32; ++q) if ((inbin & (1u << q)) && sarr[rr][q] == cmax) cnt++;
          #pragma unroll
          for (int off = 32; off >= 1; off >>= 1) cnt += __shfl_xor(cnt, off);
          if (mth <= cnt) { thresh = cmax; break; }
          mth -= cnt;
          #pragma unroll
          for (int q = 0; q < 32; ++q) if ((inbin & (1u << q)) && sarr[rr][q] == cmax) inbin &= ~(1u << q);
        }
      }
    }
    thr2[rr] = thresh; vmx2[rr] = vmax;

    float psum = 0.f;
    #pragma unroll
    for (int q = 0; q < 32; ++q) {
      float s = sarr[rr][q];
      psum += (s >= thresh) ? __expf(s - vmax) : 0.f;
    }
    #pragma unroll
    for (int off = 32; off >= 1; off >>= 1) psum += __shfl_xor(psum, off);
    if (lane == 0) psumS[rloc] = psum;
  }
  __syncthreads();

  // ---------------- phase 2: dense masked-P x V via MFMA -------------------
  const int g   = lane >> 4;
  const int n16 = lane & 15;
  const int dg  = wid & 3;          // dim group: dims dg*16..+15
  const int kh  = wid >> 2;         // key half within 256-tile
  const _Float16* VTb = VT + (size_t)bh * (DHEAD * S_LEN);
  f32x4 acc = {0.f, 0.f, 0.f, 0.f};

  #pragma unroll
  for (int kt = 0; kt < 8; ++kt) {
    // write P tile (fp16, swizzled) for this wave's 2 rows
    #pragma unroll
    for (int rr = 0; rr < 2; ++rr) {
      const int row = wid * 2 + rr;
      f16x4 pv;
      #pragma unroll
      for (int c = 0; c < 4; ++c) {
        float s = sarr[rr][kt * 4 + c];
        float p = (s >= thr2[rr]) ? __expf(s - vmx2[rr]) : 0.f;
        pv[c] = (_Float16)p;
      }
      *(f16x4*)(pbuf + ((row * 512 + lane * 8) ^ ((row & 7) << 4))) = pv;
    }
    __syncthreads();
    #pragma unroll
    for (int s = 0; s < 4; ++s) {
      f16x8 af = *(const f16x8*)(pbuf +
          ((n16 * 512 + kh * 256 + s * 64 + g * 16) ^ ((n16 & 7) << 4)));
      f16x8 bf = *(const f16x8*)(VTb + (size_t)(dg * 16 + n16) * S_LEN +
                                 kt * 256 + kh * 128 + s * 32 + g * 8);
      acc = __builtin_amdgcn_mfma_f32_16x16x32_f16(af, bf, acc, 0, 0, 0);
    }
    __syncthreads();
  }

  // reduce the two key-halves, scale by 1/psum, write out
  if (kh == 1) {
    redS[dg][lane] = make_float4(acc[0], acc[1], acc[2], acc[3]);
  }
  __syncthreads();
  if (kh == 0) {
    float4 o = redS[dg][lane];
    float ov[4] = {o.x, o.y, o.z, o.w};
    #pragma unroll
    for (int rg = 0; rg < 4; ++rg) {
      int row = g * 4 + rg;                      // C-row = P row
      float val = (acc[rg] + ov[rg]) / psumS[row];
      Out[(size_t)(rowgb + row) * DHEAD + dg * 16 + n16] = val;
    }
  }
}

// ---------------------------------------------------------------------------
// Fallback monolithic kernel (round-3, proven) for tiny ws_size
// ---------------------------------------------------------------------------
#define TQ 16
#define KT 128
#define NTILES (S_LEN / KT)
#define THREADS 512
#define LCAP 256
#define SOFF   0
#define KHI    131072
#define KLO    147456
#define HOFF   131072
#define KLOFF  147456
#define PLOFF  155648

__global__ __launch_bounds__(THREADS, 2)
void dpsa_kernel(const float* __restrict__ Q, const float* __restrict__ K,
                 const float* __restrict__ V, const int* __restrict__ nkp,
                 float* __restrict__ Out) {
  __shared__ __align__(16) char smem[163840];
  float* Sf = (float*)(smem + SOFF);

  const int tid  = (int)threadIdx.x;
  const int lane = tid & 63;
  const int wid  = tid >> 6;
  const int bid  = (int)blockIdx.x;
  const int bh   = bid >> 7;
  const int qblk = bid & 127;
  const size_t base = (size_t)bh * (size_t)(S_LEN * DHEAD);
  const float* Kbh = K + base;
  const float* Vbh = V + base;

  int nk = nkp[0];
  if (nk > S_LEN) nk = S_LEN;

  const int g = lane >> 4;
  const int m = lane & 15;

  f16x8 a_hi0, a_lo0, a_hi1, a_lo1;
  {
    const float* Qrow = Q + base + (size_t)(qblk * TQ + m) * DHEAD;
    float4 qa = *(const float4*)(Qrow + g * 8);
    float4 qb = *(const float4*)(Qrow + g * 8 + 4);
    float4 qc = *(const float4*)(Qrow + 32 + g * 8);
    float4 qd = *(const float4*)(Qrow + 32 + g * 8 + 4);
    float x[16] = {qa.x,qa.y,qa.z,qa.w, qb.x,qb.y,qb.z,qb.w,
                   qc.x,qc.y,qc.z,qc.w, qd.x,qd.y,qd.z,qd.w};
    #pragma unroll
    for (int j = 0; j < 8; ++j) {
      _Float16 h0 = (_Float16)x[j];
      a_hi0[j] = h0;  a_lo0[j] = (_Float16)(x[j] - (float)h0);
      _Float16 h1 = (_Float16)x[8 + j];
      a_hi1[j] = h1;  a_lo1[j] = (_Float16)(x[8 + j] - (float)h1);
    }
  }

  const f16x8* Kh = (const f16x8*)(smem + KHI);
  const f16x8* Kl = (const f16x8*)(smem + KLO);
  const int keyl = tid >> 2;
  const int q4i  = tid & 3;
  const int sw   = keyl & 7;

  float4 pf0, pf1, pf2, pf3;
  {
    const float4* Kg4 = (const float4*)Kbh;
    int idx = keyl * 16 + q4i * 4;
    pf0 = Kg4[idx]; pf1 = Kg4[idx + 1]; pf2 = Kg4[idx + 2]; pf3 = Kg4[idx + 3];
  }

  for (int t = 0; t < NTILES; ++t) {
    {
      float x[16] = {pf0.x,pf0.y,pf0.z,pf0.w, pf1.x,pf1.y,pf1.z,pf1.w,
                     pf2.x,pf2.y,pf2.z,pf2.w, pf3.x,pf3.y,pf3.z,pf3.w};
      f16x8 hi0, hi1, lo0, lo1;
      #pragma unroll
      for (int j = 0; j < 8; ++j) {
        _Float16 h0 = (_Float16)x[j];
        hi0[j] = h0;  lo0[j] = (_Float16)(x[j] - (float)h0);
        _Float16 h1 = (_Float16)x[8 + j];
        hi1[j] = h1;  lo1[j] = (_Float16)(x[8 + j] - (float)h1);
      }
      f16x8* KhwF = (f16x8*)(smem + KHI);
      f16x8* KlwF = (f16x8*)(smem + KLO);
      KhwF[keyl * 8 + ((q4i * 2)     ^ sw)] = hi0;
      KhwF[keyl * 8 + ((q4i * 2 + 1) ^ sw)] = hi1;
      KlwF[keyl * 8 + ((q4i * 2)     ^ sw)] = lo0;
      KlwF[keyl * 8 + ((q4i * 2 + 1) ^ sw)] = lo1;
    }
    if (t + 1 < NTILES) {
      const float4* Kg4 = (const float4*)(Kbh + (size_t)(t + 1) * (KT * DHEAD));
      int idx = keyl * 16 + q4i * 4;
      pf0 = Kg4[idx]; pf1 = Kg4[idx + 1]; pf2 = Kg4[idx + 2]; pf3 = Kg4[idx + 3];
    }
    __syncthreads();
    {
      int keyr = wid * 16 + m;
      int s0 = ( g      ^ (m & 7));
      int s1 = ((4 + g) ^ (m & 7));
      f16x8 b_hi0 = Kh[keyr * 8 + s0];
      f16x8 b_hi1 = Kh[keyr * 8 + s1];
      f16x8 b_lo0 = Kl[keyr * 8 + s0];
      f16x8 b_lo1 = Kl[keyr * 8 + s1];
      f32x4 acc = {0.f, 0.f, 0.f, 0.f};
      acc = __builtin_amdgcn_mfma_f32_16x16x32_f16(a_hi0, b_hi0, acc, 0, 0, 0);
      acc = __builtin_amdgcn_mfma_f32_16x16x32_f16(a_hi1, b_hi1, acc, 0, 0, 0);
      acc = __builtin_amdgcn_mfma_f32_16x16x32_f16(a_hi0, b_lo0, acc, 0, 0, 0);
      acc = __builtin_amdgcn_mfma_f32_16x16x32_f16(a_hi1, b_lo1, acc, 0, 0, 0);
      acc = __builtin_amdgcn_mfma_f32_16x16x32_f16(a_lo0, b_hi0, acc, 0, 0, 0);
      acc = __builtin_amdgcn_mfma_f32_16x16x32_f16(a_lo1, b_hi1, acc, 0, 0, 0);
      int keyabs = t * KT + wid * 16 + m;
      #pragma unroll
      for (int rg = 0; rg < 4; ++rg)
        Sf[(size_t)(g * 4 + rg) * S_LEN + keyabs] = acc[rg] * 0.125f;
    }
    __syncthreads();
  }

  unsigned* hw = (unsigned*)(smem + HOFF)  + wid * NBINS;
  unsigned* kl = (unsigned*)(smem + KLOFF) + wid * LCAP;
  float*    pl = (float*)(smem + PLOFF)    + wid * LCAP;
  const float4* S4 = (const float4*)(smem + SOFF);

  for (int rr = 0; rr < 2; ++rr) {
    const int row = wid * 2 + rr;
    float sarr[32];
    #pragma unroll
    for (int j = 0; j < 8; ++j) {
      float4 v4 = S4[row * (S_LEN / 4) + j * 64 + lane];
      sarr[j*4+0] = v4.x; sarr[j*4+1] = v4.y;
      sarr[j*4+2] = v4.z; sarr[j*4+3] = v4.w;
    }

    float vmax = -INFINITY, vmin = INFINITY;
    #pragma unroll
    for (int q = 0; q < 32; ++q) {
      vmax = fmaxf(vmax, sarr[q]); vmin = fminf(vmin, sarr[q]);
    }
    #pragma unroll
    for (int off = 32; off >= 1; off >>= 1) {
      vmax = fmaxf(vmax, __shfl_xor(vmax, off));
      vmin = fminf(vmin, __shfl_xor(vmin, off));
    }

    float thresh = -INFINITY;
    if (nk > 0) {
      float range = vmax - vmin;
      float scale = (range > 0.f) ? ((float)NBINS / range) : 0.f;
      #pragma unroll
      for (int i2 = 0; i2 < BPL; ++i2) hw[(i2 << 6) | lane] = 0u;
      #pragma unroll
      for (int q = 0; q < 32; ++q) {
        int bb = (int)((sarr[q] - vmin) * scale);
        bb = bb < 0 ? 0 : (bb > NBINS - 1 ? NBINS - 1 : bb);
        atomicAdd(&hw[((bb & 7) << 6) | (bb >> 3)], 1u);
      }
      unsigned A = 0; unsigned hv[BPL];
      #pragma unroll
      for (int i2 = 0; i2 < BPL; ++i2) { hv[i2] = hw[(i2 << 6) | lane]; A += hv[i2]; }
      unsigned ssum = A;
      #pragma unroll
      for (int off = 1; off <= 32; off <<= 1) {
        unsigned u = (unsigned)__shfl_down((int)ssum, off);
        if (lane + off < 64) ssum += u;
      }
      unsigned cum = ssum - A;
      int bsel = -1; int mloc = 0;
      #pragma unroll
      for (int i2 = BPL - 1; i2 >= 0; --i2) {
        unsigned c0 = cum; cum += hv[i2];
        if (bsel < 0 && c0 < (unsigned)nk && cum >= (unsigned)nk) {
          bsel = (lane << 3) | i2; mloc = nk - (int)c0;
        }
      }
      unsigned long long fmk = __ballot(bsel >= 0);
      int srcl = __ffsll(fmk) - 1;
      bsel = __shfl(bsel, srcl);
      int mth = __shfl(mloc, srcl);

      unsigned inbin = 0;
      #pragma unroll
      for (int q = 0; q < 32; ++q) {
        int bb = (int)((sarr[q] - vmin) * scale);
        bb = bb < 0 ? 0 : (bb > NBINS - 1 ? NBINS - 1 : bb);
        if (bb == bsel) inbin |= (1u << q);
      }
      while (true) {
        float cmax = -INFINITY;
        #pragma unroll
        for (int q = 0; q < 32; ++q) if (inbin & (1u << q)) cmax = fmaxf(cmax, sarr[q]);
        #pragma unroll
        for (int off = 32; off >= 1; off >>= 1) cmax = fmaxf(cmax, __shfl_xor(cmax, off));
        int cnt = 0;
        #pragma unroll
        for (int q = 0; q < 32; ++q) if ((inbin & (1u << q)) && sarr[q] == cmax) cnt++;
        #pragma unroll
        for (int off = 32; off >= 1; off >>= 1) cnt += __shfl_xor(cnt, off);
        if (mth <= cnt) { thresh = cmax; break; }
        mth -= cnt;
        #pragma unroll
        for (int q = 0; q < 32; ++q) if ((inbin & (1u << q)) && sarr[q] == cmax) inbin &= ~(1u << q);
      }
    }

    float psum = 0.f;
    #pragma unroll
    for (int q = 0; q < 32; ++q) {
      float p = (sarr[q] >= thresh) ? expf(sarr[q] - vmax) : 0.f;
      sarr[q] = p; psum += p;
    }
    #pragma unroll
    for (int off = 32; off >= 1; off >>= 1) psum += __shfl_xor(psum, off);

    unsigned nkept = 0;
    #pragma unroll
    for (int q = 0; q < 32; ++q) {
      bool keep = sarr[q] > 0.f;
      unsigned long long mk = __ballot(keep);
      if (keep) {
        unsigned idx = nkept + (unsigned)__popcll(mk & ((1ull << lane) - 1ull));
        if (idx < LCAP) {
          kl[idx] = (unsigned)((q >> 2) * 256 + lane * 4 + (q & 3));
          pl[idx] = sarr[q];
        }
      }
      nkept += (unsigned)__popcll(mk);
    }

    float acc0 = 0.f, acc1 = 0.f, acc2 = 0.f, acc3 = 0.f;
    if (nkept <= LCAP) {
      unsigned i = 0;
      for (; i + 4 <= nkept; i += 4) {
        acc0 = fmaf(pl[i+0], Vbh[(size_t)kl[i+0] * DHEAD + lane], acc0);
        acc1 = fmaf(pl[i+1], Vbh[(size_t)kl[i+1] * DHEAD + lane], acc1);
        acc2 = fmaf(pl[i+2], Vbh[(size_t)kl[i+2] * DHEAD + lane], acc2);
        acc3 = fmaf(pl[i+3], Vbh[(size_t)kl[i+3] * DHEAD + lane], acc3);
      }
      for (; i < nkept; ++i)
        acc0 = fmaf(pl[i], Vbh[(size_t)kl[i] * DHEAD + lane], acc0);
    } else {
      #pragma unroll
      for (int q = 0; q < 32; ++q) {
        for (int sl = 0; sl < 64; ++sl) {
          float pp = __shfl(sarr[q], sl);
          if (pp > 0.f)
            acc0 = fmaf(pp, Vbh[(size_t)((q >> 2) * 256 + sl * 4 + (q & 3)) * DHEAD + lane], acc0);
        }
      }
    }
    float accv = (acc0 + acc1) + (acc2 + acc3);
    Out[base + (size_t)(qblk * TQ + row) * DHEAD + lane] = accv / psum;
  }
}

extern "C" void kernel_launch(void* const* d_in, const int* in_sizes, int n_in,
                              void* d_out, int out_size, void* d_ws, size_t ws_size,
                              hipStream_t stream) {
  const float* q  = (const float*)d_in[0];
  const float* k  = (const float*)d_in[1];
  const float* v  = (const float*)d_in[2];
  const int*   nk = (const int*)d_in[3];
  float* out = (float*)d_out;

  size_t srem = (ws_size > VT_BYTES) ? (ws_size - VT_BYTES) : 0;
  size_t maxrows = srem / ((size_t)S_LEN * sizeof(float));
  long long chunk = (long long)(maxrows / 512) * 512;
  if (chunk > NROWS) chunk = NROWS;

  if (chunk >= 512) {
    _Float16* vt = (_Float16*)d_ws;
    float* sws = (float*)((char*)d_ws + VT_BYTES);
    prep_vt<<<dim3(512), dim3(256), 0, stream>>>(v, vt);
    for (int row0 = 0; row0 < NROWS; row0 += (int)chunk) {
      int rows = (NROWS - row0 < (int)chunk) ? (NROWS - row0) : (int)chunk;
      qk_kernel<<<dim3(rows / 8), dim3(256), 0, stream>>>(q, k, sws, row0);
      selmm_kernel<<<dim3(rows / 16), dim3(512), 0, stream>>>(sws, vt, nk, out, row0);
    }
  } else {
    dpsa_kernel<<<dim3(8192), dim3(THREADS), 0, stream>>>(q, k, v, nk, out);
  }
}